// Round 7
// baseline (1527.699 us; speedup 1.0000x reference)
//
#include <hip/hip_runtime.h>

#define NX 128
#define NSTEPS 4096

typedef float f2 __attribute__((ext_vector_type(2)));
typedef float f4 __attribute__((ext_vector_type(4)));

union F4 {
  f4 v;
  f2 h[2];
  float s[4];
};

// packed fp32 FMA: d = a*b + d on both 32-bit halves (full-rate on CDNA)
__device__ __forceinline__ void pk_fma(f2& d, f2 a, f2 b) {
  asm("v_pk_fma_f32 %0, %1, %2, %0" : "+v"(d) : "v"(a), "v"(b));
}

// v + DPP-moved v (quad_perm etc.)
template <int CTRL>
__device__ __forceinline__ float dpp_add_f(float v) {
  int i = __float_as_int(v);
  int s = __builtin_amdgcn_update_dpp(i, i, CTRL, 0xf, 0xf, false);
  return v + __int_as_float(s);
}

__launch_bounds__(256, 1)
__global__ void nmpc_rollout_kernel(const float* __restrict__ x0,
                                    const float* __restrict__ xref,
                                    const float* __restrict__ useq,
                                    const float* __restrict__ A,
                                    const float* __restrict__ B,
                                    float* __restrict__ out) {
  // x stored as 2 slices of 64 floats, 68-word stride: per ds_read_b128 the
  // two broadcast addresses (words 4q vs 68+4q) land in disjoint bank quads.
  __shared__ __align__(16) float xs0[136];
  __shared__ __align__(16) float xs1[136];
  __shared__ float2 us[NSTEPS];  // interleaved (u0[s], u1[s]) pairs, 32KB
  __shared__ double wsum[4];

  const int t = threadIdx.x;
  const int r = t >> 1;  // row 0..127 (a pair of lanes per row)
  const int p = t & 1;   // column half 0..1 (64 cols each)

  // ---- one-time staging of useq into LDS (interleaved pairs) ----
#pragma unroll
  for (int k = 0; k < NSTEPS / 256; ++k) {
    int idx = k * 256 + t;
    us[idx] = make_float2(useq[idx], useq[NSTEPS + idx]);
  }

  // ---- A fragment: row r, cols 64p..64p+63, prescaled by 2*log2(e) so the
  // dot product directly feeds exp2 (removes a mul from the serial chain) ----
  const float K = 2.8853900817779268f;
  F4 a[16];
#pragma unroll
  for (int q = 0; q < 16; ++q) {
    f4 v = *(const f4*)(A + r * NX + 64 * p + 4 * q);
    a[q].v = v * K;
  }
  const float b0 = B[2 * r] * K;
  const float b1 = B[2 * r + 1] * K;

  // fp64 master state (accuracy anchor); xf = f32 image used for the matvec.
  double x_cur = (double)x0[r];
  float xf = (float)x_cur;
  double mse;
  {
    double d = x_cur - (double)xref[r];
    mse = d * d;  // accumulated on BOTH pair lanes -> final sum / 2
  }
  if (p == 0) xs0[68 * (r >> 6) + (r & 63)] = xf;
  asm volatile("s_waitcnt lgkmcnt(0)" ::: "memory");
  __builtin_amdgcn_s_barrier();
  asm volatile("" ::: "memory");

  // ---- 4-deep rolling prefetch of xref rows (consumed off the x-chain) ----
  float xr0 = xref[1 * NX + r];
  float xr1 = xref[2 * NX + r];
  float xr2 = xref[3 * NX + r];
  float xr3 = xref[4 * NX + r];

  auto step = [&](const float* __restrict__ src, float* __restrict__ dst, int s) {
    float2 uv = us[s];  // broadcast pair; consumed off-chain (bu)
    int nref = (s + 5 <= NSTEPS) ? (s + 5) : NSTEPS;
    float xnew = xref[nref * NX + r];

    // ---- fused read+FMA: 16x ds_read_b128 (2 bcast addrs, conflict-free),
    //      32 pk_fma in 4 independent chains (depth 8) ----
    const f4* xb = (const f4*)(src + 68 * p);
    f2 c0 = (f2)(0.f), c1 = (f2)(0.f), c2 = (f2)(0.f), c3 = (f2)(0.f);
#pragma unroll
    for (int q = 0; q < 16; q += 2) {
      F4 xa, xc;
      xa.v = xb[q];
      xc.v = xb[q + 1];
      pk_fma(c0, a[q].h[0], xa.h[0]);
      pk_fma(c1, a[q].h[1], xa.h[1]);
      pk_fma(c2, a[q + 1].h[0], xc.h[0]);
      pk_fma(c3, a[q + 1].h[1], xc.h[1]);
    }
    float bu = fmaf(b1, uv.y, b0 * uv.x);  // off critical path

    f2 s01 = c0 + c1;
    f2 s23 = c2 + c3;
    f2 ss = s01 + s23;
    float sum = ss.x + ss.y;
    sum = dpp_add_f<0xB1>(sum);  // pair exchange: both lanes get full row dot

    // zk = 2*log2(e) * z ; tanh(z) = 1 - 2/(exp2(zk)+1), saturates at +-1
    float zk = sum + bu;
    float e = __builtin_amdgcn_exp2f(zk);
    float xd = fmaf(-2.f, __builtin_amdgcn_rcpf(e + 1.f), 1.f);

    // chain: one f32 add then store; f64 state update happens off-chain
    float xf_new = xf + xd;
    if (p == 0) dst[68 * (r >> 6) + (r & 63)] = xf_new;

    x_cur += (double)xd;    // off-chain f64 master state
    xf = (float)x_cur;      // re-anchor for next step (off-chain)
    double d = x_cur - (double)xr0;  // xr0 loaded 4 steps ago
    mse = fma(d, d, mse);

    // raw barrier: drain LDS ops only; vmem prefetches stay in flight
    asm volatile("s_waitcnt lgkmcnt(0)" ::: "memory");
    __builtin_amdgcn_s_barrier();
    asm volatile("" ::: "memory");

    xr0 = xr1; xr1 = xr2; xr2 = xr3; xr3 = xnew;  // SSA-renamed by unroll
  };

#pragma unroll 1
  for (int s = 0; s < NSTEPS; s += 4) {
    step(xs0, xs1, s);
    step(xs1, xs0, s + 1);
    step(xs0, xs1, s + 2);
    step(xs1, xs0, s + 3);
  }

  // ---- final reduction (each row counted twice -> /2) ----
#pragma unroll
  for (int off = 1; off < 64; off <<= 1) mse += __shfl_xor(mse, off, 64);
  if ((t & 63) == 0) wsum[t >> 6] = mse;
  __syncthreads();
  if (t == 0) {
    double tot = wsum[0] + wsum[1] + wsum[2] + wsum[3];
    out[0] = (float)(tot / (2.0 * (double)((NSTEPS + 1) * NX)));
  }
}

extern "C" void kernel_launch(void* const* d_in, const int* in_sizes, int n_in,
                              void* d_out, int out_size, void* d_ws, size_t ws_size,
                              hipStream_t stream) {
  const float* x0 = (const float*)d_in[0];
  const float* xref = (const float*)d_in[1];
  const float* useq = (const float*)d_in[2];
  const float* A = (const float*)d_in[3];
  const float* B = (const float*)d_in[4];
  float* out = (float*)d_out;

  nmpc_rollout_kernel<<<dim3(1), dim3(256), 0, stream>>>(x0, xref, useq, A, B, out);
}

// Round 8
// 1391.973 us; speedup vs baseline: 1.0975x; 1.0975x over previous
//
#include <hip/hip_runtime.h>

#define NX 128
#define NSTEPS 4096

typedef float f2 __attribute__((ext_vector_type(2)));
typedef float f4 __attribute__((ext_vector_type(4)));

union F4 {
  f4 v;
  f2 h[2];
  float s[4];
};

// packed fp32 FMA: d = a*b + d on both 32-bit halves (full-rate on CDNA)
__device__ __forceinline__ void pk_fma(f2& d, f2 a, f2 b) {
  asm("v_pk_fma_f32 %0, %1, %2, %0" : "+v"(d) : "v"(a), "v"(b));
}

// v + DPP-moved v (quad_perm / mirrors)
template <int CTRL>
__device__ __forceinline__ float dpp_add_f(float v) {
  int i = __float_as_int(v);
  int s = __builtin_amdgcn_update_dpp(i, i, CTRL, 0xf, 0xf, false);
  return v + __int_as_float(s);
}

__launch_bounds__(256, 1)
__global__ void nmpc_rollout_kernel(const float* __restrict__ x0,
                                    const float* __restrict__ xref,
                                    const float* __restrict__ useq,
                                    const float* __restrict__ A,
                                    const float* __restrict__ B,
                                    float* __restrict__ out) {
  // x stored as 8 slices of 16 floats padded to 20 words (80B stride):
  // per ds_read_b128 the 8 broadcast groups start at banks
  // (20p)%32 = {0,20,8,28,16,4,24,12} -> disjoint bank quads, conflict-free.
  __shared__ __align__(16) float xs0[160];
  __shared__ __align__(16) float xs1[160];
  __shared__ float2 us[NSTEPS];  // interleaved (u0[s], u1[s]) pairs, 32KB
  __shared__ double wsum[4];

  const int t = threadIdx.x;
  const int g = t >> 3;      // row-group 0..31 (4 rows each)
  const int p = t & 7;       // column part 0..7 (16 cols each)
  const int r = 4 * g + (p & 3);  // row this lane finalizes (2 lanes per row)

  // ---- one-time staging of useq into LDS (interleaved pairs) ----
#pragma unroll
  for (int k = 0; k < NSTEPS / 256; ++k) {
    int idx = k * 256 + t;
    us[idx] = make_float2(useq[idx], useq[NSTEPS + idx]);
  }

  // ---- A fragment: rows 4g..4g+3, cols 16p..16p+15, prescaled by 2*log2(e)
  // so the dot product feeds exp2 directly (no mul on the serial chain) ----
  const float K = 2.8853900817779268f;
  F4 a[4][4];
#pragma unroll
  for (int j = 0; j < 4; ++j) {
#pragma unroll
    for (int q = 0; q < 4; ++q) {
      f4 v = *(const f4*)(A + (4 * g + j) * NX + 16 * p + 4 * q);
      a[j][q].v = v * K;
    }
  }
  const float b0 = B[2 * r] * K;
  const float b1 = B[2 * r + 1] * K;

  // fp64 master state (accuracy anchor); xf = f32 image used for the matvec.
  double x_cur = (double)x0[r];
  float xf = (float)x_cur;
  double mse;
  {
    double d = x_cur - (double)xref[r];
    mse = d * d;  // both pair-lanes accumulate -> final sum / 2
  }
  if (p < 4) xs0[20 * (r >> 4) + (r & 15)] = xf;
  asm volatile("s_waitcnt lgkmcnt(0)" ::: "memory");
  __builtin_amdgcn_s_barrier();
  asm volatile("" ::: "memory");

  // ---- 4-deep rolling prefetch of xref rows (consumed off the x-chain) ----
  float xr0 = xref[1 * NX + r];
  float xr1 = xref[2 * NX + r];
  float xr2 = xref[3 * NX + r];
  float xr3 = xref[4 * NX + r];

  auto step = [&](const float* __restrict__ src, float* __restrict__ dst, int s) {
    // ---- x slice first (FMA-critical; DS returns in-order) ----
    const f4* xb = (const f4*)(src + 20 * p);
    F4 xv0, xv1, xv2, xv3;
    xv0.v = xb[0]; xv1.v = xb[1]; xv2.v = xb[2]; xv3.v = xb[3];
    float2 uv = us[s];  // broadcast pair; consumed off-chain
    int nref = (s + 5 <= NSTEPS) ? (s + 5) : NSTEPS;
    float xnew = xref[nref * NX + r];

    // ---- 4 rows x 16 cols via packed FMAs: 32 pk-fma, 8 indep chains ----
    f2 ae[4], ao[4];
#pragma unroll
    for (int j = 0; j < 4; ++j) { ae[j] = (f2)(0.f); ao[j] = (f2)(0.f); }
#pragma unroll
    for (int j = 0; j < 4; ++j) {
      pk_fma(ae[j], a[j][0].h[0], xv0.h[0]);
      pk_fma(ao[j], a[j][0].h[1], xv0.h[1]);
      pk_fma(ae[j], a[j][1].h[0], xv1.h[0]);
      pk_fma(ao[j], a[j][1].h[1], xv1.h[1]);
      pk_fma(ae[j], a[j][2].h[0], xv2.h[0]);
      pk_fma(ao[j], a[j][2].h[1], xv2.h[1]);
      pk_fma(ae[j], a[j][3].h[0], xv3.h[0]);
      pk_fma(ao[j], a[j][3].h[1], xv3.h[1]);
    }
    float bu = fmaf(b1, uv.y, b0 * uv.x);  // off critical path

    float acc0, acc1, acc2, acc3;
    {
      f2 h0 = ae[0] + ao[0];
      f2 h1 = ae[1] + ao[1];
      f2 h2 = ae[2] + ao[2];
      f2 h3 = ae[3] + ao[3];
      acc0 = h0.x + h0.y;
      acc1 = h1.x + h1.y;
      acc2 = h2.x + h2.y;
      acc3 = h3.x + h3.y;
    }

    // ---- all-DPP 8-part reduce; after half_mirror ALL 8 lanes hold the
    // full row sums (quad0<->quad1 swap since quads are uniform) ----
    acc0 = dpp_add_f<0xB1>(acc0);   // quad_perm [1,0,3,2]  xor1
    acc1 = dpp_add_f<0xB1>(acc1);
    acc2 = dpp_add_f<0xB1>(acc2);
    acc3 = dpp_add_f<0xB1>(acc3);
    acc0 = dpp_add_f<0x4E>(acc0);   // quad_perm [2,3,0,1]  xor2
    acc1 = dpp_add_f<0x4E>(acc1);
    acc2 = dpp_add_f<0x4E>(acc2);
    acc3 = dpp_add_f<0x4E>(acc3);
    acc0 = dpp_add_f<0x141>(acc0);  // row_half_mirror: lane i <-> 7-i
    acc1 = dpp_add_f<0x141>(acc1);
    acc2 = dpp_add_f<0x141>(acc2);
    acc3 = dpp_add_f<0x141>(acc3);

    // 2-cndmask select: lane p (and p+4) takes row 4g + (p&3)
    float a01 = (p & 1) ? acc1 : acc0;
    float a23 = (p & 1) ? acc3 : acc2;
    float sum = (p & 2) ? a23 : a01;

    // ---- tail on ALL lanes (2x redundant, no divergence) ----
    float zk = sum + bu;  // already scaled by 2*log2(e)
    float e = __builtin_amdgcn_exp2f(zk);
    float xd = fmaf(-2.f, __builtin_amdgcn_rcpf(e + 1.f), 1.f);  // tanh
    float xf_new = xf + xd;              // chain: one f32 add then store
    if (p < 4) dst[20 * (r >> 4) + (r & 15)] = xf_new;

    x_cur += (double)xd;                 // off-chain f64 master state
    xf = (float)x_cur;                   // re-anchor (off-chain)
    double d = x_cur - (double)xr0;      // xr0 loaded 4 steps ago
    mse = fma(d, d, mse);

    // raw barrier: drain LDS ops only; vmem prefetches stay in flight
    asm volatile("s_waitcnt lgkmcnt(0)" ::: "memory");
    __builtin_amdgcn_s_barrier();
    asm volatile("" ::: "memory");

    xr0 = xr1; xr1 = xr2; xr2 = xr3; xr3 = xnew;  // SSA-renamed by unroll
  };

#pragma unroll 1
  for (int s = 0; s < NSTEPS; s += 4) {
    step(xs0, xs1, s);
    step(xs1, xs0, s + 1);
    step(xs0, xs1, s + 2);
    step(xs1, xs0, s + 3);
  }

  // ---- final reduction (each row counted twice -> /2) ----
#pragma unroll
  for (int off = 1; off < 64; off <<= 1) mse += __shfl_xor(mse, off, 64);
  if ((t & 63) == 0) wsum[t >> 6] = mse;
  __syncthreads();
  if (t == 0) {
    double tot = wsum[0] + wsum[1] + wsum[2] + wsum[3];
    out[0] = (float)(tot / (2.0 * (double)((NSTEPS + 1) * NX)));
  }
}

extern "C" void kernel_launch(void* const* d_in, const int* in_sizes, int n_in,
                              void* d_out, int out_size, void* d_ws, size_t ws_size,
                              hipStream_t stream) {
  const float* x0 = (const float*)d_in[0];
  const float* xref = (const float*)d_in[1];
  const float* useq = (const float*)d_in[2];
  const float* A = (const float*)d_in[3];
  const float* B = (const float*)d_in[4];
  float* out = (float*)d_out;

  nmpc_rollout_kernel<<<dim3(1), dim3(256), 0, stream>>>(x0, xref, useq, A, B, out);
}